// Round 5
// baseline (15302.022 us; speedup 1.0000x reference)
//
#include <hip/hip_runtime.h>
#include <hip/hip_bf16.h>
#include <math.h>

#define L_IN 1549
#define S_OUT 512

typedef __hip_bfloat16 bf16;
typedef __attribute__((ext_vector_type(8))) short bfrag;    // 8 bf16 (4 VGPRs)
typedef __attribute__((ext_vector_type(4))) float f32x4;    // MFMA accumulator

__device__ __forceinline__ float bfbits2f(unsigned short u) {
    union { unsigned int i; float f; } x;
    x.i = ((unsigned int)u) << 16;
    return x.f;
}
__device__ __forceinline__ float4 ld4bf(const bf16* p) {   // 4 bf16 (8B) -> float4
    union { uint2 u; unsigned short s[4]; } w;
    w.u = *(const uint2*)p;
    return make_float4(bfbits2f(w.s[0]), bfbits2f(w.s[1]), bfbits2f(w.s[2]), bfbits2f(w.s[3]));
}
// device-scope (cross-XCD-safe) scalar accesses for the h exchange
__device__ __forceinline__ void st_dev(float* p, float v) {
    __hip_atomic_store(p, v, __ATOMIC_RELAXED, __HIP_MEMORY_SCOPE_AGENT);
}
__device__ __forceinline__ float ld_dev(const float* p) {
    return __hip_atomic_load(p, __ATOMIC_RELAXED, __HIP_MEMORY_SCOPE_AGENT);
}

// ---------------------------------------------------------------------------
// conv1d(k=16,pad=1) + BN + ReLU + maxpool(3,3) + transpose -> h0 (B,512,32) bf16
// ---------------------------------------------------------------------------
__global__ __launch_bounds__(256) void conv_bn_pool(
    const float* __restrict__ x, const float* __restrict__ w,
    const float* __restrict__ cb, const float* __restrict__ gamma,
    const float* __restrict__ beta, const float* __restrict__ mean,
    const float* __restrict__ var, bf16* __restrict__ h0)
{
    int b  = blockIdx.y;
    int sg = blockIdx.x;
    __shared__ float xs[32][40];
    int tid = threadIdx.x;
    int base = sg * 24;
    for (int i = tid; i < 32 * 40; i += 256) {
        int ci = i / 40, dl = i % 40;
        int l = base - 1 + dl;
        xs[ci][dl] = (l >= 0 && l < L_IN) ? x[(size_t)(b * 32 + ci) * L_IN + l] : 0.f;
    }
    __syncthreads();
    int c = tid & 31, sl = tid >> 5;
    float scale = gamma[c] * rsqrtf(var[c] + 1e-5f);
    float shift = beta[c] - mean[c] * scale;
    float bias = cb[c];
    float best = -1e30f;
    #pragma unroll
    for (int p = 0; p < 3; ++p) {
        float acc = bias;
        for (int ci = 0; ci < 32; ++ci) {
            const float* wr = w + (size_t)(c * 32 + ci) * 16;
            int off = 3 * sl + p;
            #pragma unroll
            for (int kk = 0; kk < 16; ++kk) acc += xs[ci][off + kk] * wr[kk];
        }
        float y = acc * scale + shift;
        y = fmaxf(y, 0.f);
        best = fmaxf(best, y);
    }
    int s = sg * 8 + sl;
    h0[((size_t)b * S_OUT + s) * 32 + c] = __float2bfloat16(best);
}

// ---------------------------------------------------------------------------
// fp32 -> bf16 elementwise pack
// ---------------------------------------------------------------------------
__global__ void pack_bf16(const float* __restrict__ src, bf16* __restrict__ dst, int n)
{
    int i = blockIdx.x * 256 + threadIdx.x;
    if (i < n) dst[i] = __float2bfloat16(src[i]);
}

// ---------------------------------------------------------------------------
// Pack W_hh (1024,256) fp32 -> two column-split slices (p=0,1), each
// [k8 0..31][col 0..511][jj 0..7] bf16  (one float4 = 8 consecutive k for one
// col).  col = seg*128 + cl maps to gate row g = seg*256 + p*128 + cl.
// ---------------------------------------------------------------------------
__global__ void pack_whh_split(const float* __restrict__ W, bf16* __restrict__ out)
{
    int i = blockIdx.x * 256 + threadIdx.x;   // 262144 total (2 slices x 131072)
    int p = i >> 17;
    int rem = i & 131071;
    int k8 = rem >> 12;
    int colj = rem & 4095;
    int col = colj >> 3;
    int jj = colj & 7;
    int k = k8 * 8 + jj;
    int seg = col >> 7, cl = col & 127;
    int g = seg * 256 + p * 128 + cl;
    out[i] = __float2bfloat16(W[(size_t)g * 256 + k]);
}

// ---------------------------------------------------------------------------
// MFMA bf16 GEMM:  C = A @ B^T + bias.  (unchanged from round 4)
// ---------------------------------------------------------------------------
__global__ __launch_bounds__(256) void gemm_mfma(
    const bf16* __restrict__ A,
    const bf16* __restrict__ Bm0, const bf16* __restrict__ Bm1, const bf16* __restrict__ Bm2,
    const float* __restrict__ bs0, const float* __restrict__ bs1, const float* __restrict__ bs2,
    bf16* __restrict__ Cm0, bf16* __restrict__ Cm1, bf16* __restrict__ Cm2,
    int M, int N, int K)
{
    int z = blockIdx.z;
    const bf16* B = (z == 0) ? Bm0 : ((z == 1) ? Bm1 : Bm2);
    const float* bias = (z == 0) ? bs0 : ((z == 1) ? bs1 : bs2);
    bf16* C = (z == 0) ? Cm0 : ((z == 1) ? Cm1 : Cm2);

    __shared__ bf16 As[128 * 32];
    __shared__ bf16 Bs[128 * 32];

    int tid = threadIdx.x;
    int lane = tid & 63;
    int wave = tid >> 6;
    int bm = blockIdx.y, bn = blockIdx.x;
    int wm = (wave >> 1) * 64;
    int wn = (wave & 1) * 64;

    int sr = tid >> 2;
    int sc = (tid & 3) * 8;
    const bf16* Ag = A + (size_t)(bm * 128 + sr) * K + sc;
    const bf16* Bg = B + (size_t)(bn * 128 + sr) * K + sc;

    int fm = lane & 15;
    int fk = (lane >> 4) * 8;

    f32x4 acc[4][4];
    #pragma unroll
    for (int i = 0; i < 4; ++i)
        #pragma unroll
        for (int j = 0; j < 4; ++j) acc[i][j] = (f32x4)(0.f);

    for (int k0 = 0; k0 < K; k0 += 32) {
        float4 a0 = *(const float4*)(Ag + k0);
        float4 a1 = *(const float4*)(Ag + (size_t)64 * K + k0);
        float4 b0 = *(const float4*)(Bg + k0);
        float4 b1 = *(const float4*)(Bg + (size_t)64 * K + k0);
        __syncthreads();
        *(float4*)(As + sr * 32 + sc)        = a0;
        *(float4*)(As + (sr + 64) * 32 + sc) = a1;
        *(float4*)(Bs + sr * 32 + sc)        = b0;
        *(float4*)(Bs + (sr + 64) * 32 + sc) = b1;
        __syncthreads();

        bfrag af[4], bfr[4];
        #pragma unroll
        for (int i = 0; i < 4; ++i)
            af[i] = *(const bfrag*)(As + (wm + i * 16 + fm) * 32 + fk);
        #pragma unroll
        for (int j = 0; j < 4; ++j)
            bfr[j] = *(const bfrag*)(Bs + (wn + j * 16 + fm) * 32 + fk);
        #pragma unroll
        for (int i = 0; i < 4; ++i)
            #pragma unroll
            for (int j = 0; j < 4; ++j)
                acc[i][j] = __builtin_amdgcn_mfma_f32_16x16x32_bf16(
                    af[i], bfr[j], acc[i][j], 0, 0, 0);
    }

    int rbase = (lane >> 4) * 4;
    #pragma unroll
    for (int j = 0; j < 4; ++j) {
        int n = bn * 128 + wn + j * 16 + (lane & 15);
        float bv = bias[n];
        #pragma unroll
        for (int i = 0; i < 4; ++i) {
            #pragma unroll
            for (int r = 0; r < 4; ++r) {
                int m = bm * 128 + wm + i * 16 + rbase + r;
                C[(size_t)m * N + n] = __float2bfloat16(acc[i][j][r] + bv);
            }
        }
    }
}

// ---------------------------------------------------------------------------
// LSTM recurrence v3: column-split x2.  256 blocks x 512 threads; block
// (u, p) owns h positions [p*128,(p+1)*128) of unit u=(b,dir) and the 512
// gate columns {i,f,g,o} at those positions (weight slice 256 KB bf16,
// streamed from L2 each step).  Cross-block h exchange: phase A does MACs
// over the OWN h-half (available locally) while the partner publishes its
// half via device-scope stores + flag; phase B covers the partner half.
// Ws: per layer, 4 slices [(dir*2+p)][k8 0..31][col 0..511][8 bf16].
// hx: 256 x 128 f32; flags: 256 u32 (memset 0 per launch).
// ---------------------------------------------------------------------------
__global__ __launch_bounds__(512) void lstm_pair(
    const bf16* __restrict__ xg_f, const bf16* __restrict__ xg_b,
    const bf16* __restrict__ Ws, bf16* __restrict__ out,
    float* __restrict__ hx, unsigned int* __restrict__ flags)
{
    int bid = blockIdx.x;        // 0..255
    int u = bid >> 1;            // unit
    int p = bid & 1;             // h-half
    int b = u & 63;
    int dir = u >> 6;
    const bf16* xg = dir ? xg_b : xg_f;
    const float4* W4 = (const float4*)(Ws + (size_t)((dir << 1) | p) * 131072);

    int t = threadIdx.x;         // 0..511
    int seg = t >> 7;            // gate segment (i,f,g,o)
    int cl = t & 127;            // position within half
    int gcol = seg * 256 + p * 128 + cl;    // global gate column

    __shared__ __align__(16) float hs[256];   // full h of this unit
    __shared__ float gsh[512];                // gate partial exchange

    if (t < 256) hs[t] = 0.f;
    float cst = 0.f;
    __syncthreads();

    unsigned int* pflag = flags + (bid ^ 1);
    const float* phx = hx + (size_t)(bid ^ 1) * 128;
    float* ohx = hx + (size_t)bid * 128;

    const float4* hs4 = (const float4*)hs;

    for (int step = 0; step < 512; ++step) {
        int ts = dir ? (511 - step) : step;
        float acc = __bfloat162float(xg[((size_t)b * 512 + ts) * 1024 + gcol]);

        // phase A: own-k half (k in [p*128, p*128+128))
        int kb = p * 16;
        #pragma unroll 8
        for (int k8 = 0; k8 < 16; ++k8) {
            union { float4 f; unsigned short s[8]; } w;
            w.f = W4[(size_t)(kb + k8) * 512 + t];
            float4 h0v = hs4[(kb + k8) * 2];
            float4 h1v = hs4[(kb + k8) * 2 + 1];
            acc += bfbits2f(w.s[0]) * h0v.x + bfbits2f(w.s[1]) * h0v.y
                 + bfbits2f(w.s[2]) * h0v.z + bfbits2f(w.s[3]) * h0v.w
                 + bfbits2f(w.s[4]) * h1v.x + bfbits2f(w.s[5]) * h1v.y
                 + bfbits2f(w.s[6]) * h1v.z + bfbits2f(w.s[7]) * h1v.w;
        }

        // sync with partner: need its h from step-1 (step 0: zeros, already set)
        if (step > 0) {
            if (t == 0) {
                while (__hip_atomic_load(pflag, __ATOMIC_ACQUIRE,
                                         __HIP_MEMORY_SCOPE_AGENT) < (unsigned)step)
                    __builtin_amdgcn_s_sleep(1);
            }
            __syncthreads();
            if (t < 128) hs[(1 - p) * 128 + t] = ld_dev(phx + t);
            __syncthreads();
        }

        // phase B: partner-k half
        int kc = (1 - p) * 16;
        #pragma unroll 8
        for (int k8 = 0; k8 < 16; ++k8) {
            union { float4 f; unsigned short s[8]; } w;
            w.f = W4[(size_t)(kc + k8) * 512 + t];
            float4 h0v = hs4[(kc + k8) * 2];
            float4 h1v = hs4[(kc + k8) * 2 + 1];
            acc += bfbits2f(w.s[0]) * h0v.x + bfbits2f(w.s[1]) * h0v.y
                 + bfbits2f(w.s[2]) * h0v.z + bfbits2f(w.s[3]) * h0v.w
                 + bfbits2f(w.s[4]) * h1v.x + bfbits2f(w.s[5]) * h1v.y
                 + bfbits2f(w.s[6]) * h1v.z + bfbits2f(w.s[7]) * h1v.w;
        }

        gsh[t] = acc;
        __syncthreads();

        if (t < 128) {
            float gi = gsh[t], gf = gsh[128 + t], gg = gsh[256 + t], go = gsh[384 + t];
            float si = 1.f / (1.f + expf(-gi));
            float sf = 1.f / (1.f + expf(-gf));
            float so = 1.f / (1.f + expf(-go));
            cst = sf * cst + si * tanhf(gg);
            float h = so * tanhf(cst);
            hs[p * 128 + t] = h;              // own half for next step
            st_dev(ohx + t, h);               // publish to partner
            out[((size_t)b * 512 + ts) * 512 + dir * 256 + p * 128 + t] =
                __float2bfloat16(h);
        }
        __syncthreads();                       // h writes done (vmcnt drained)
        if (t == 0)
            __hip_atomic_store(flags + bid, (unsigned)(step + 1),
                               __ATOMIC_RELEASE, __HIP_MEMORY_SCOPE_AGENT);
    }
}

// ---------------------------------------------------------------------------
// Fused attention (unchanged from round 4).
// ---------------------------------------------------------------------------
__global__ __launch_bounds__(256) void attention(
    const bf16* __restrict__ q, const bf16* __restrict__ k, const bf16* __restrict__ v,
    const bf16* o1, bf16* r)
{
    __shared__ float qs[8 * 520];
    __shared__ float ks[8 * 520];
    __shared__ float vs[8 * 520];
    __shared__ float la[64 * 9];
    int b = blockIdx.y;
    int s0 = blockIdx.x * 8;
    int tid = threadIdx.x;

    for (int i = tid; i < 512; i += 256) {
        int row = i >> 6, L = i & 63;
        const bf16* gp = q + ((size_t)(b * 512 + s0 + row)) * 512;
        float4 f0 = ld4bf(gp + 4 * L);
        float4 f1 = ld4bf(gp + 256 + 4 * L);
        *(float4*)&qs[row * 520 + 4 * L] = f0;
        *(float4*)&qs[row * 520 + 256 + 4 * L] = f1;
    }

    int hh = tid >> 6;
    int tt = (tid >> 3) & 7;
    int ss = tid & 7;
    int g = ss * 8 + tt;
    int cs = tid >> 5;
    int nb = tid & 31;

    float ctx[16];
    #pragma unroll
    for (int j = 0; j < 16; ++j) ctx[j] = 0.f;

    for (int tc = 0; tc < 512; tc += 8) {
        __syncthreads();
        for (int i = tid; i < 512; i += 256) {
            int row = i >> 6, L = i & 63;
            size_t gb = ((size_t)(b * 512 + tc + row)) * 512;
            float4 k0 = ld4bf(k + gb + 4 * L);
            float4 k1 = ld4bf(k + gb + 256 + 4 * L);
            float4 v0 = ld4bf(v + gb + 4 * L);
            float4 v1 = ld4bf(v + gb + 256 + 4 * L);
            *(float4*)&ks[row * 520 + 4 * L] = k0;
            *(float4*)&ks[row * 520 + 256 + 4 * L] = k1;
            *(float4*)&vs[row * 520 + 4 * L] = v0;
            *(float4*)&vs[row * 520 + 256 + 4 * L] = v1;
        }
        __syncthreads();

        #pragma unroll
        for (int u = 0; u < 2; ++u) {
            int h = hh + 4 * u;
            const float4* qp = (const float4*)&qs[ss * 520 + h * 64];
            const float4* kp = (const float4*)&ks[tt * 520 + h * 64];
            float a = 0.f;
            #pragma unroll
            for (int d4 = 0; d4 < 16; ++d4) {
                float4 qv = qp[d4], kv = kp[d4];
                a += qv.x * kv.x + qv.y * kv.y + qv.z * kv.z + qv.w * kv.w;
            }
            la[g * 9 + h] = a * 0.125f;
        }
        __syncthreads();

        if (tid < 64) {
            float s[8];
            float m = -1e30f;
            #pragma unroll
            for (int h = 0; h < 8; ++h) { s[h] = la[tid * 9 + h]; m = fmaxf(m, s[h]); }
            float sum = 0.f;
            #pragma unroll
            for (int h = 0; h < 8; ++h) sum += expf(s[h] - m);
            float lse = m + logf(sum);
            #pragma unroll
            for (int h = 0; h < 8; ++h) la[tid * 9 + h] = s[h] - lse;
        }
        __syncthreads();

        #pragma unroll
        for (int t8 = 0; t8 < 8; ++t8) {
            float lav[8];
            #pragma unroll
            for (int h = 0; h < 8; ++h) lav[h] = la[(cs * 8 + t8) * 9 + h];
            #pragma unroll
            for (int j = 0; j < 16; ++j) {
                int n = nb + (j << 5);
                ctx[j] += lav[j >> 1] * vs[t8 * 520 + n];
            }
        }
    }
    size_t base = ((size_t)(b * 512 + s0 + cs)) * 512;
    #pragma unroll
    for (int j = 0; j < 16; ++j) {
        int n = nb + (j << 5);
        float o = __bfloat162float(o1[base + n]);
        r[base + n] = __float2bfloat16(o + ctx[j]);
    }
}

// ---------------------------------------------------------------------------
// LayerNorm(last dim) -> mean over S -> fc.  One block per (b, s) row.
// ---------------------------------------------------------------------------
__device__ __forceinline__ float block_sum(float val, float* red, int tid)
{
    #pragma unroll
    for (int o = 32; o > 0; o >>= 1) val += __shfl_down(val, o);
    __syncthreads();
    if ((tid & 63) == 0) red[tid >> 6] = val;
    __syncthreads();
    return red[0] + red[1] + red[2] + red[3];
}

__global__ __launch_bounds__(256) void ln_pool_fc(
    const bf16* __restrict__ r, const float* __restrict__ g, const float* __restrict__ bt,
    const float* __restrict__ fcw, const float* __restrict__ fcb, float* __restrict__ out)
{
    __shared__ float red[4];
    int b = blockIdx.y, s = blockIdx.x, tid = threadIdx.x;
    const bf16* row = r + ((size_t)(b * 512 + s)) * 512;
    __hip_bfloat162 rv = *(const __hip_bfloat162*)(row + tid * 2);
    float v0 = __bfloat162float(rv.x), v1 = __bfloat162float(rv.y);
    float tot = block_sum(v0 + v1, red, tid);
    float mu = tot * (1.f / 512.f);
    float d0 = v0 - mu, d1 = v1 - mu;
    float sq = block_sum(d0 * d0 + d1 * d1, red, tid);
    float rs = rsqrtf(sq * (1.f / 512.f) + 1e-5f);
    int n0 = tid * 2;
    float term = d0 * rs * g[n0] * fcw[n0] + d1 * rs * g[n0 + 1] * fcw[n0 + 1];
    if (s == 0) term += 512.f * (bt[n0] * fcw[n0] + bt[n0 + 1] * fcw[n0 + 1]);
    float D = block_sum(term, red, tid);
    if (tid == 0) {
        float val = D * (1.f / 512.f);
        if (s == 0) val += fcb[0];
        atomicAdd(out + b, val);
    }
}

// ---------------------------------------------------------------------------
// Workspace layout (< 200 MiB):
//   [0,64M)        xgf bf16            -> later q,k
//   [64,128M)      xgb bf16            -> later v
//   [128,160M)     out0 bf16
//   [160,192M)     out1 bf16 (attention in-place)
//   [192,194M)     h0 bf16
//   [194M..)       lstm W slices (2 layers x 4 slices x 131072 bf16),
//                  bf16 proj weights, hx (32768 f32), flags (512 u32)
// ---------------------------------------------------------------------------
extern "C" void kernel_launch(void* const* d_in, const int* in_sizes, int n_in,
                              void* d_out, int out_size, void* d_ws, size_t ws_size,
                              hipStream_t stream)
{
    (void)in_sizes; (void)n_in; (void)ws_size;
    const float* x      = (const float*)d_in[0];
    const float* conv_w = (const float*)d_in[1];
    const float* conv_b = (const float*)d_in[2];
    const float* bn_g   = (const float*)d_in[3];
    const float* bn_b   = (const float*)d_in[4];
    const float* bn_m   = (const float*)d_in[5];
    const float* bn_v   = (const float*)d_in[6];
    const float* W_ih0f = (const float*)d_in[7];
    const float* W_hh0f = (const float*)d_in[8];
    const float* b0f    = (const float*)d_in[9];
    const float* W_ih0b = (const float*)d_in[10];
    const float* W_hh0b = (const float*)d_in[11];
    const float* b0b    = (const float*)d_in[12];
    const float* W_ih1f = (const float*)d_in[13];
    const float* W_hh1f = (const float*)d_in[14];
    const float* b1f    = (const float*)d_in[15];
    const float* W_ih1b = (const float*)d_in[16];
    const float* W_hh1b = (const float*)d_in[17];
    const float* b1b    = (const float*)d_in[18];
    const float* Wq = (const float*)d_in[19];
    const float* bq = (const float*)d_in[20];
    const float* Wk = (const float*)d_in[21];
    const float* bk = (const float*)d_in[22];
    const float* Wv = (const float*)d_in[23];
    const float* bv = (const float*)d_in[24];
    const float* ln_g = (const float*)d_in[25];
    const float* ln_b = (const float*)d_in[26];
    const float* fc_w = (const float*)d_in[27];
    const float* fc_b = (const float*)d_in[28];
    float* out = (float*)d_out;

    char* ws = (char*)d_ws;
    bf16* xgf  = (bf16*)ws;                               // 33,554,432
    bf16* xgb  = xgf + 33554432;                          // 33,554,432
    bf16* out0 = (bf16*)(ws + 134217728);                 // 16,777,216
    bf16* out1 = (bf16*)(ws + 167772160);                 // 16,777,216
    bf16* h0   = (bf16*)(ws + 201326592);                 // 1,048,576
    bf16* wsl0 = (bf16*)(ws + 203423744);                 // 524,288 (4 slices)
    bf16* wsl1 = wsl0 + 524288;                           // 524,288 (4 slices)
    bf16* wbih0f = wsl1 + 524288;                         // 32,768
    bf16* wbih0b = wbih0f + 32768;                        // 32,768
    bf16* wbih1f = wbih0b + 32768;                        // 524,288
    bf16* wbih1b = wbih1f + 524288;                       // 524,288
    bf16* wbq    = wbih1b + 524288;                       // 262,144
    bf16* wbk    = wbq + 262144;                          // 262,144
    bf16* wbv    = wbk + 262144;                          // 262,144
    float* hx    = (float*)(wbv + 262144);                // 32,768 f32
    unsigned int* flags0 = (unsigned int*)(hx + 32768);   // 256 u32
    unsigned int* flags1 = flags0 + 256;                  // 256 u32
    // q,k,v alias the (dead after lstm1) xg region
    bf16* qb = xgf;
    bf16* kb = xgf + 16777216;
    bf16* vb = xgb;

    hipMemsetAsync(d_out, 0, (size_t)out_size * sizeof(float), stream);
    hipMemsetAsync(flags0, 0, 512 * sizeof(unsigned int), stream);

    pack_whh_split<<<1024, 256, 0, stream>>>(W_hh0f, wsl0);
    pack_whh_split<<<1024, 256, 0, stream>>>(W_hh0b, wsl0 + 262144);
    pack_whh_split<<<1024, 256, 0, stream>>>(W_hh1f, wsl1);
    pack_whh_split<<<1024, 256, 0, stream>>>(W_hh1b, wsl1 + 262144);
    pack_bf16<<<128, 256, 0, stream>>>(W_ih0f, wbih0f, 32768);
    pack_bf16<<<128, 256, 0, stream>>>(W_ih0b, wbih0b, 32768);
    pack_bf16<<<2048, 256, 0, stream>>>(W_ih1f, wbih1f, 524288);
    pack_bf16<<<2048, 256, 0, stream>>>(W_ih1b, wbih1b, 524288);
    pack_bf16<<<1024, 256, 0, stream>>>(Wq, wbq, 262144);
    pack_bf16<<<1024, 256, 0, stream>>>(Wk, wbk, 262144);
    pack_bf16<<<1024, 256, 0, stream>>>(Wv, wbv, 262144);

    conv_bn_pool<<<dim3(64, 64), 256, 0, stream>>>(
        x, conv_w, conv_b, bn_g, bn_b, bn_m, bn_v, h0);

    // layer-0 input projections (K=32), fwd+bwd in one launch
    gemm_mfma<<<dim3(8, 256, 2), 256, 0, stream>>>(
        h0, wbih0f, wbih0b, nullptr, b0f, b0b, nullptr, xgf, xgb, nullptr,
        32768, 1024, 32);

    lstm_pair<<<256, 512, 0, stream>>>(xgf, xgb, wsl0, out0, hx, flags0);

    // layer-1 input projections (K=512)
    gemm_mfma<<<dim3(8, 256, 2), 256, 0, stream>>>(
        out0, wbih1f, wbih1b, nullptr, b1f, b1b, nullptr, xgf, xgb, nullptr,
        32768, 1024, 512);

    lstm_pair<<<256, 512, 0, stream>>>(xgf, xgb, wsl1, out1, hx, flags1);

    // QKV projections (N=512), 3-way
    gemm_mfma<<<dim3(4, 256, 3), 256, 0, stream>>>(
        out1, wbq, wbk, wbv, bq, bk, bv, qb, kb, vb,
        32768, 512, 512);

    attention<<<dim3(64, 64), 256, 0, stream>>>(qb, kb, vb, out1, out1);

    ln_pool_fc<<<dim3(512, 64), 256, 0, stream>>>(out1, ln_g, ln_b, fc_w, fc_b, out);
}

// Round 6
// 5293.441 us; speedup vs baseline: 2.8908x; 2.8908x over previous
//
#include <hip/hip_runtime.h>
#include <hip/hip_bf16.h>
#include <math.h>

#define L_IN 1549
#define S_OUT 512

typedef __hip_bfloat16 bf16;
typedef __attribute__((ext_vector_type(8))) short bfrag;    // 8 bf16 (4 VGPRs)
typedef __attribute__((ext_vector_type(4))) float f32x4;    // MFMA accumulator

__device__ __forceinline__ float bfbits2f(unsigned short u) {
    union { unsigned int i; float f; } x;
    x.i = ((unsigned int)u) << 16;
    return x.f;
}
__device__ __forceinline__ unsigned short f2bfbits(float f) {
    union { float f; unsigned int i; } x; x.f = f;
    unsigned int lsb = (x.i >> 16) & 1;
    return (unsigned short)((x.i + 0x7fff + lsb) >> 16);
}
__device__ __forceinline__ float4 ld4bf(const bf16* p) {   // 4 bf16 (8B) -> float4
    union { uint2 u; unsigned short s[4]; } w;
    w.u = *(const uint2*)p;
    return make_float4(bfbits2f(w.s[0]), bfbits2f(w.s[1]), bfbits2f(w.s[2]), bfbits2f(w.s[3]));
}

// bf16-pair dot product: c + lo(w)*lo(h) + hi(w)*hi(h)
#if __has_builtin(__builtin_amdgcn_fdot2_f32_bf16)
typedef __attribute__((ext_vector_type(2))) __bf16 v2bf;
__device__ __forceinline__ float dot2bf(unsigned int w, unsigned int h, float c) {
    union { unsigned int u; v2bf v; } a, b;
    a.u = w; b.u = h;
    return __builtin_amdgcn_fdot2_f32_bf16(a.v, b.v, c, false);
}
#else
__device__ __forceinline__ float dot2bf(unsigned int w, unsigned int h, float c) {
    union { unsigned int i; float f; } w0, w1, h0, h1;
    w0.i = w << 16; w1.i = w & 0xffff0000u;
    h0.i = h << 16; h1.i = h & 0xffff0000u;
    return c + w0.f * h0.f + w1.f * h1.f;
}
#endif

// ---------------------------------------------------------------------------
// conv1d(k=16,pad=1) + BN + ReLU + maxpool(3,3) + transpose -> h0 (B,512,32) bf16
// ---------------------------------------------------------------------------
__global__ __launch_bounds__(256) void conv_bn_pool(
    const float* __restrict__ x, const float* __restrict__ w,
    const float* __restrict__ cb, const float* __restrict__ gamma,
    const float* __restrict__ beta, const float* __restrict__ mean,
    const float* __restrict__ var, bf16* __restrict__ h0)
{
    int b  = blockIdx.y;
    int sg = blockIdx.x;
    __shared__ float xs[32][40];
    int tid = threadIdx.x;
    int base = sg * 24;
    for (int i = tid; i < 32 * 40; i += 256) {
        int ci = i / 40, dl = i % 40;
        int l = base - 1 + dl;
        xs[ci][dl] = (l >= 0 && l < L_IN) ? x[(size_t)(b * 32 + ci) * L_IN + l] : 0.f;
    }
    __syncthreads();
    int c = tid & 31, sl = tid >> 5;
    float scale = gamma[c] * rsqrtf(var[c] + 1e-5f);
    float shift = beta[c] - mean[c] * scale;
    float bias = cb[c];
    float best = -1e30f;
    #pragma unroll
    for (int p = 0; p < 3; ++p) {
        float acc = bias;
        for (int ci = 0; ci < 32; ++ci) {
            const float* wr = w + (size_t)(c * 32 + ci) * 16;
            int off = 3 * sl + p;
            #pragma unroll
            for (int kk = 0; kk < 16; ++kk) acc += xs[ci][off + kk] * wr[kk];
        }
        float y = acc * scale + shift;
        y = fmaxf(y, 0.f);
        best = fmaxf(best, y);
    }
    int s = sg * 8 + sl;
    h0[((size_t)b * S_OUT + s) * 32 + c] = __float2bfloat16(best);
}

// ---------------------------------------------------------------------------
// fp32 -> bf16 elementwise pack
// ---------------------------------------------------------------------------
__global__ void pack_bf16(const float* __restrict__ src, bf16* __restrict__ dst, int n)
{
    int i = blockIdx.x * 256 + threadIdx.x;
    if (i < n) dst[i] = __float2bfloat16(src[i]);
}

// ---------------------------------------------------------------------------
// Pack W_hh (1024,256) fp32 for lstm_reg.  Output: 131072 dwords per set.
// dword = bf16pair( W[g][2kp], W[g][2kp+1] ), g = 2t+col.
//  R (reg,   kp   0..99):  i = kp*1024 + col*512 + t           [0,102400)
//  L (LDS,   kp 100..113): i = 102400 + (kp-100)*1024 + 2t+col [102400,116736)
//  S (stream,kp 114..127): i = 116736 + (kp-114)*1024 + 2t+col [116736,131072)
// ---------------------------------------------------------------------------
__global__ void pack_lstm(const float* __restrict__ W, unsigned int* __restrict__ out)
{
    int i = blockIdx.x * 256 + threadIdx.x;   // 0..131071
    int kp, t, col;
    if (i < 102400) {
        kp = i >> 10; col = (i >> 9) & 1; t = i & 511;
    } else if (i < 116736) {
        int j = i - 102400;
        kp = 100 + (j >> 10); t = (j & 1023) >> 1; col = j & 1;
    } else {
        int j = i - 116736;
        kp = 114 + (j >> 10); t = (j & 1023) >> 1; col = j & 1;
    }
    int g = 2 * t + col;
    unsigned int lo = f2bfbits(W[(size_t)g * 256 + 2 * kp]);
    unsigned int hi = f2bfbits(W[(size_t)g * 256 + 2 * kp + 1]);
    out[i] = lo | (hi << 16);
}

// ---------------------------------------------------------------------------
// MFMA bf16 GEMM:  C = A @ B^T + bias.  (unchanged from round 4)
// ---------------------------------------------------------------------------
__global__ __launch_bounds__(256) void gemm_mfma(
    const bf16* __restrict__ A,
    const bf16* __restrict__ Bm0, const bf16* __restrict__ Bm1, const bf16* __restrict__ Bm2,
    const float* __restrict__ bs0, const float* __restrict__ bs1, const float* __restrict__ bs2,
    bf16* __restrict__ Cm0, bf16* __restrict__ Cm1, bf16* __restrict__ Cm2,
    int M, int N, int K)
{
    int z = blockIdx.z;
    const bf16* B = (z == 0) ? Bm0 : ((z == 1) ? Bm1 : Bm2);
    const float* bias = (z == 0) ? bs0 : ((z == 1) ? bs1 : bs2);
    bf16* C = (z == 0) ? Cm0 : ((z == 1) ? Cm1 : Cm2);

    __shared__ bf16 As[128 * 32];
    __shared__ bf16 Bs[128 * 32];

    int tid = threadIdx.x;
    int lane = tid & 63;
    int wave = tid >> 6;
    int bm = blockIdx.y, bn = blockIdx.x;
    int wm = (wave >> 1) * 64;
    int wn = (wave & 1) * 64;

    int sr = tid >> 2;
    int sc = (tid & 3) * 8;
    const bf16* Ag = A + (size_t)(bm * 128 + sr) * K + sc;
    const bf16* Bg = B + (size_t)(bn * 128 + sr) * K + sc;

    int fm = lane & 15;
    int fk = (lane >> 4) * 8;

    f32x4 acc[4][4];
    #pragma unroll
    for (int i = 0; i < 4; ++i)
        #pragma unroll
        for (int j = 0; j < 4; ++j) acc[i][j] = (f32x4)(0.f);

    for (int k0 = 0; k0 < K; k0 += 32) {
        float4 a0 = *(const float4*)(Ag + k0);
        float4 a1 = *(const float4*)(Ag + (size_t)64 * K + k0);
        float4 b0 = *(const float4*)(Bg + k0);
        float4 b1 = *(const float4*)(Bg + (size_t)64 * K + k0);
        __syncthreads();
        *(float4*)(As + sr * 32 + sc)        = a0;
        *(float4*)(As + (sr + 64) * 32 + sc) = a1;
        *(float4*)(Bs + sr * 32 + sc)        = b0;
        *(float4*)(Bs + (sr + 64) * 32 + sc) = b1;
        __syncthreads();

        bfrag af[4], bfr[4];
        #pragma unroll
        for (int i = 0; i < 4; ++i)
            af[i] = *(const bfrag*)(As + (wm + i * 16 + fm) * 32 + fk);
        #pragma unroll
        for (int j = 0; j < 4; ++j)
            bfr[j] = *(const bfrag*)(Bs + (wn + j * 16 + fm) * 32 + fk);
        #pragma unroll
        for (int i = 0; i < 4; ++i)
            #pragma unroll
            for (int j = 0; j < 4; ++j)
                acc[i][j] = __builtin_amdgcn_mfma_f32_16x16x32_bf16(
                    af[i], bfr[j], acc[i][j], 0, 0, 0);
    }

    int rbase = (lane >> 4) * 4;
    #pragma unroll
    for (int j = 0; j < 4; ++j) {
        int n = bn * 128 + wn + j * 16 + (lane & 15);
        float bv = bias[n];
        #pragma unroll
        for (int i = 0; i < 4; ++i) {
            #pragma unroll
            for (int r = 0; r < 4; ++r) {
                int m = bm * 128 + wm + i * 16 + rbase + r;
                C[(size_t)m * N + n] = __float2bfloat16(acc[i][j][r] + bv);
            }
        }
    }
}

// ---------------------------------------------------------------------------
// LSTM recurrence v4: on-chip weights.  One block per (batch,dir), 512 thr,
// 2 waves/SIMD.  Thread t owns gate cols (2t, 2t+1) for full K=256:
//   kp 0..99   -> 200 register dwords (bf16 pairs)
//   kp 100..113 -> LDS (56 KB, staged once)
//   kp 114..127 -> streamed from L2 each step (56 KB/step)
// h exchanged as bf16 pairs in LDS; cell state fp32 in registers.
// No cross-block communication; out-write off the critical path.
// ---------------------------------------------------------------------------
__global__ __launch_bounds__(512, 2) void lstm_reg(
    const bf16* __restrict__ xg_f, const bf16* __restrict__ xg_b,
    const unsigned int* __restrict__ Wl, bf16* __restrict__ out)
{
    int u = blockIdx.x;          // 0..127
    int b = u & 63, dir = u >> 6;
    const unsigned int* W = Wl + (size_t)dir * 131072;
    const bf16* xg = dir ? xg_b : xg_f;
    int t = threadIdx.x;         // 0..511

    __shared__ unsigned int lw[14336];               // 56 KB weight slice
    __shared__ __align__(16) unsigned int hs2[128];  // h bf16 pairs
    __shared__ float gsh[1024];                      // gates

    // load register-resident weights (coalesced: lanes over t)
    unsigned int wr[200];
    #pragma unroll
    for (int j = 0; j < 200; ++j) wr[j] = W[j * 512 + t];
    // stage LDS weights
    for (int i = t; i < 14336; i += 512) lw[i] = W[102400 + i];
    if (t < 128) hs2[t] = 0u;
    float c0 = 0.f, c1 = 0.f;
    __syncthreads();

    const unsigned int* Wst = W + 116736;

    for (int step = 0; step < 512; ++step) {
        int ts = dir ? (511 - step) : step;

        // issue stream + xg loads first (latency overlapped with reg MACs)
        uint2 sw[14];
        #pragma unroll
        for (int s = 0; s < 14; ++s)
            sw[s] = *(const uint2*)(Wst + s * 1024 + 2 * t);
        unsigned int xv =
            *(const unsigned int*)(xg + ((size_t)b * 512 + ts) * 1024 + 2 * t);

        float a0 = 0.f, a1 = 0.f;
        // register part: kp 0..99 (h broadcast as uint4)
        #pragma unroll
        for (int q = 0; q < 25; ++q) {
            uint4 hv = *(const uint4*)&hs2[q * 4];
            #pragma unroll
            for (int r = 0; r < 4; ++r) {
                int kp = q * 4 + r;
                unsigned int h2 = (&hv.x)[r];
                a0 = dot2bf(wr[kp * 2], h2, a0);
                a1 = dot2bf(wr[kp * 2 + 1], h2, a1);
            }
        }
        // LDS part: kp 100..113
        #pragma unroll
        for (int r = 0; r < 14; ++r) {
            uint2 wv = *(const uint2*)&lw[r * 1024 + 2 * t];
            unsigned int h2 = hs2[100 + r];
            a0 = dot2bf(wv.x, h2, a0);
            a1 = dot2bf(wv.y, h2, a1);
        }
        // stream part: kp 114..127
        #pragma unroll
        for (int s = 0; s < 14; ++s) {
            unsigned int h2 = hs2[114 + s];
            a0 = dot2bf(sw[s].x, h2, a0);
            a1 = dot2bf(sw[s].y, h2, a1);
        }
        a0 += bfbits2f((unsigned short)(xv & 0xffff));
        a1 += bfbits2f((unsigned short)(xv >> 16));

        __syncthreads();                     // hs2 reads done
        *(float2*)&gsh[2 * t] = make_float2(a0, a1);
        __syncthreads();

        if (t < 128) {
            float gi0 = gsh[2 * t],       gi1 = gsh[2 * t + 1];
            float gf0 = gsh[256 + 2 * t], gf1 = gsh[257 + 2 * t];
            float gg0 = gsh[512 + 2 * t], gg1 = gsh[513 + 2 * t];
            float go0 = gsh[768 + 2 * t], go1 = gsh[769 + 2 * t];
            float si0 = 1.f / (1.f + expf(-gi0)), si1 = 1.f / (1.f + expf(-gi1));
            float sf0 = 1.f / (1.f + expf(-gf0)), sf1 = 1.f / (1.f + expf(-gf1));
            float so0 = 1.f / (1.f + expf(-go0)), so1 = 1.f / (1.f + expf(-go1));
            c0 = sf0 * c0 + si0 * tanhf(gg0);
            c1 = sf1 * c1 + si1 * tanhf(gg1);
            float h0 = so0 * tanhf(c0);
            float h1 = so1 * tanhf(c1);
            unsigned int hp = (unsigned int)f2bfbits(h0)
                            | ((unsigned int)f2bfbits(h1) << 16);
            hs2[t] = hp;
            *(unsigned int*)(out + ((size_t)b * 512 + ts) * 512 + dir * 256 + 2 * t) = hp;
        }
        __syncthreads();
    }
}

// ---------------------------------------------------------------------------
// Fused attention (round-4 version, conflict-free staging + head-softmax).
// ---------------------------------------------------------------------------
__global__ __launch_bounds__(256) void attention(
    const bf16* __restrict__ q, const bf16* __restrict__ k, const bf16* __restrict__ v,
    const bf16* o1, bf16* r)
{
    __shared__ float qs[8 * 520];
    __shared__ float ks[8 * 520];
    __shared__ float vs[8 * 520];
    __shared__ float la[64 * 9];
    int b = blockIdx.y;
    int s0 = blockIdx.x * 8;
    int tid = threadIdx.x;

    for (int i = tid; i < 512; i += 256) {
        int row = i >> 6, L = i & 63;
        const bf16* gp = q + ((size_t)(b * 512 + s0 + row)) * 512;
        float4 f0 = ld4bf(gp + 4 * L);
        float4 f1 = ld4bf(gp + 256 + 4 * L);
        *(float4*)&qs[row * 520 + 4 * L] = f0;
        *(float4*)&qs[row * 520 + 256 + 4 * L] = f1;
    }

    int hh = tid >> 6;
    int tt = (tid >> 3) & 7;
    int ss = tid & 7;
    int g = ss * 8 + tt;
    int cs = tid >> 5;
    int nb = tid & 31;

    float ctx[16];
    #pragma unroll
    for (int j = 0; j < 16; ++j) ctx[j] = 0.f;

    for (int tc = 0; tc < 512; tc += 8) {
        __syncthreads();
        for (int i = tid; i < 512; i += 256) {
            int row = i >> 6, L = i & 63;
            size_t gb = ((size_t)(b * 512 + tc + row)) * 512;
            float4 k0 = ld4bf(k + gb + 4 * L);
            float4 k1 = ld4bf(k + gb + 256 + 4 * L);
            float4 v0 = ld4bf(v + gb + 4 * L);
            float4 v1 = ld4bf(v + gb + 256 + 4 * L);
            *(float4*)&ks[row * 520 + 4 * L] = k0;
            *(float4*)&ks[row * 520 + 256 + 4 * L] = k1;
            *(float4*)&vs[row * 520 + 4 * L] = v0;
            *(float4*)&vs[row * 520 + 256 + 4 * L] = v1;
        }
        __syncthreads();

        #pragma unroll
        for (int uu = 0; uu < 2; ++uu) {
            int h = hh + 4 * uu;
            const float4* qp = (const float4*)&qs[ss * 520 + h * 64];
            const float4* kp = (const float4*)&ks[tt * 520 + h * 64];
            float a = 0.f;
            #pragma unroll
            for (int d4 = 0; d4 < 16; ++d4) {
                float4 qv = qp[d4], kv = kp[d4];
                a += qv.x * kv.x + qv.y * kv.y + qv.z * kv.z + qv.w * kv.w;
            }
            la[g * 9 + h] = a * 0.125f;
        }
        __syncthreads();

        if (tid < 64) {
            float s[8];
            float m = -1e30f;
            #pragma unroll
            for (int h = 0; h < 8; ++h) { s[h] = la[tid * 9 + h]; m = fmaxf(m, s[h]); }
            float sum = 0.f;
            #pragma unroll
            for (int h = 0; h < 8; ++h) sum += expf(s[h] - m);
            float lse = m + logf(sum);
            #pragma unroll
            for (int h = 0; h < 8; ++h) la[tid * 9 + h] = s[h] - lse;
        }
        __syncthreads();

        #pragma unroll
        for (int t8 = 0; t8 < 8; ++t8) {
            float lav[8];
            #pragma unroll
            for (int h = 0; h < 8; ++h) lav[h] = la[(cs * 8 + t8) * 9 + h];
            #pragma unroll
            for (int j = 0; j < 16; ++j) {
                int n = nb + (j << 5);
                ctx[j] += lav[j >> 1] * vs[t8 * 520 + n];
            }
        }
    }
    size_t base = ((size_t)(b * 512 + s0 + cs)) * 512;
    #pragma unroll
    for (int j = 0; j < 16; ++j) {
        int n = nb + (j << 5);
        float o = __bfloat162float(o1[base + n]);
        r[base + n] = __float2bfloat16(o + ctx[j]);
    }
}

// ---------------------------------------------------------------------------
// LayerNorm(last dim) -> mean over S -> fc.  One block per (b, s) row.
// ---------------------------------------------------------------------------
__device__ __forceinline__ float block_sum(float val, float* red, int tid)
{
    #pragma unroll
    for (int o = 32; o > 0; o >>= 1) val += __shfl_down(val, o);
    __syncthreads();
    if ((tid & 63) == 0) red[tid >> 6] = val;
    __syncthreads();
    return red[0] + red[1] + red[2] + red[3];
}

__global__ __launch_bounds__(256) void ln_pool_fc(
    const bf16* __restrict__ r, const float* __restrict__ g, const float* __restrict__ bt,
    const float* __restrict__ fcw, const float* __restrict__ fcb, float* __restrict__ out)
{
    __shared__ float red[4];
    int b = blockIdx.y, s = blockIdx.x, tid = threadIdx.x;
    const bf16* row = r + ((size_t)(b * 512 + s)) * 512;
    __hip_bfloat162 rv = *(const __hip_bfloat162*)(row + tid * 2);
    float v0 = __bfloat162float(rv.x), v1 = __bfloat162float(rv.y);
    float tot = block_sum(v0 + v1, red, tid);
    float mu = tot * (1.f / 512.f);
    float d0 = v0 - mu, d1 = v1 - mu;
    float sq = block_sum(d0 * d0 + d1 * d1, red, tid);
    float rs = rsqrtf(sq * (1.f / 512.f) + 1e-5f);
    int n0 = tid * 2;
    float term = d0 * rs * g[n0] * fcw[n0] + d1 * rs * g[n0 + 1] * fcw[n0 + 1];
    if (s == 0) term += 512.f * (bt[n0] * fcw[n0] + bt[n0 + 1] * fcw[n0 + 1]);
    float D = block_sum(term, red, tid);
    if (tid == 0) {
        float val = D * (1.f / 512.f);
        if (s == 0) val += fcb[0];
        atomicAdd(out + b, val);
    }
}

// ---------------------------------------------------------------------------
// Workspace layout (< 200 MiB):
//   [0,64M)        xgf bf16            -> later q,k
//   [64,128M)      xgb bf16            -> later v
//   [128,160M)     out0 bf16
//   [160,192M)     out1 bf16 (attention in-place)
//   [192,194M)     h0 bf16
//   [194,196M)     wl0 (2 sets x 131072 dwords)
//   [195..196M)    wl1
//   then bf16 proj weights
// ---------------------------------------------------------------------------
extern "C" void kernel_launch(void* const* d_in, const int* in_sizes, int n_in,
                              void* d_out, int out_size, void* d_ws, size_t ws_size,
                              hipStream_t stream)
{
    (void)in_sizes; (void)n_in; (void)ws_size;
    const float* x      = (const float*)d_in[0];
    const float* conv_w = (const float*)d_in[1];
    const float* conv_b = (const float*)d_in[2];
    const float* bn_g   = (const float*)d_in[3];
    const float* bn_b   = (const float*)d_in[4];
    const float* bn_m   = (const float*)d_in[5];
    const float* bn_v   = (const float*)d_in[6];
    const float* W_ih0f = (const float*)d_in[7];
    const float* W_hh0f = (const float*)d_in[8];
    const float* b0f    = (const float*)d_in[9];
    const float* W_ih0b = (const float*)d_in[10];
    const float* W_hh0b = (const float*)d_in[11];
    const float* b0b    = (const float*)d_in[12];
    const float* W_ih1f = (const float*)d_in[13];
    const float* W_hh1f = (const float*)d_in[14];
    const float* b1f    = (const float*)d_in[15];
    const float* W_ih1b = (const float*)d_in[16];
    const float* W_hh1b = (const float*)d_in[17];
    const float* b1b    = (const float*)d_in[18];
    const float* Wq = (const float*)d_in[19];
    const float* bq = (const float*)d_in[20];
    const float* Wk = (const float*)d_in[21];
    const float* bk = (const float*)d_in[22];
    const float* Wv = (const float*)d_in[23];
    const float* bv = (const float*)d_in[24];
    const float* ln_g = (const float*)d_in[25];
    const float* ln_b = (const float*)d_in[26];
    const float* fc_w = (const float*)d_in[27];
    const float* fc_b = (const float*)d_in[28];
    float* out = (float*)d_out;

    char* ws = (char*)d_ws;
    bf16* xgf  = (bf16*)ws;                               // 33,554,432
    bf16* xgb  = xgf + 33554432;                          // 33,554,432
    bf16* out0 = (bf16*)(ws + 134217728);                 // 16,777,216
    bf16* out1 = (bf16*)(ws + 167772160);                 // 16,777,216
    bf16* h0   = (bf16*)(ws + 201326592);                 // 1,048,576
    unsigned int* wl0 = (unsigned int*)(ws + 203423744);  // 262,144 dwords
    unsigned int* wl1 = wl0 + 262144;                     // 262,144 dwords
    bf16* wbih0f = (bf16*)(wl1 + 262144);                 // 32,768
    bf16* wbih0b = wbih0f + 32768;                        // 32,768
    bf16* wbih1f = wbih0b + 32768;                        // 524,288
    bf16* wbih1b = wbih1f + 524288;                       // 524,288
    bf16* wbq    = wbih1b + 524288;                       // 262,144
    bf16* wbk    = wbq + 262144;                          // 262,144
    bf16* wbv    = wbk + 262144;                          // 262,144
    // q,k,v alias the (dead after lstm1) xg region
    bf16* qb = xgf;
    bf16* kb = xgf + 16777216;
    bf16* vb = xgb;

    hipMemsetAsync(d_out, 0, (size_t)out_size * sizeof(float), stream);

    pack_lstm<<<512, 256, 0, stream>>>(W_hh0f, wl0);
    pack_lstm<<<512, 256, 0, stream>>>(W_hh0b, wl0 + 131072);
    pack_lstm<<<512, 256, 0, stream>>>(W_hh1f, wl1);
    pack_lstm<<<512, 256, 0, stream>>>(W_hh1b, wl1 + 131072);
    pack_bf16<<<128, 256, 0, stream>>>(W_ih0f, wbih0f, 32768);
    pack_bf16<<<128, 256, 0, stream>>>(W_ih0b, wbih0b, 32768);
    pack_bf16<<<2048, 256, 0, stream>>>(W_ih1f, wbih1f, 524288);
    pack_bf16<<<2048, 256, 0, stream>>>(W_ih1b, wbih1b, 524288);
    pack_bf16<<<1024, 256, 0, stream>>>(Wq, wbq, 262144);
    pack_bf16<<<1024, 256, 0, stream>>>(Wk, wbk, 262144);
    pack_bf16<<<1024, 256, 0, stream>>>(Wv, wbv, 262144);

    conv_bn_pool<<<dim3(64, 64), 256, 0, stream>>>(
        x, conv_w, conv_b, bn_g, bn_b, bn_m, bn_v, h0);

    // layer-0 input projections (K=32), fwd+bwd in one launch
    gemm_mfma<<<dim3(8, 256, 2), 256, 0, stream>>>(
        h0, wbih0f, wbih0b, nullptr, b0f, b0b, nullptr, xgf, xgb, nullptr,
        32768, 1024, 32);

    lstm_reg<<<128, 512, 0, stream>>>(xgf, xgb, wl0, out0);

    // layer-1 input projections (K=512)
    gemm_mfma<<<dim3(8, 256, 2), 256, 0, stream>>>(
        out0, wbih1f, wbih1b, nullptr, b1f, b1b, nullptr, xgf, xgb, nullptr,
        32768, 1024, 512);

    lstm_reg<<<128, 512, 0, stream>>>(xgf, xgb, wl1, out1);

    // QKV projections (N=512), 3-way
    gemm_mfma<<<dim3(4, 256, 3), 256, 0, stream>>>(
        out1, wbq, wbk, wbv, bq, bk, bv, qb, kb, vb,
        32768, 512, 512);

    attention<<<dim3(64, 64), 256, 0, stream>>>(qb, kb, vb, out1, out1);

    ln_pool_fc<<<dim3(512, 64), 256, 0, stream>>>(out1, ln_g, ln_b, fc_w, fc_b, out);
}

// Round 7
// 3962.912 us; speedup vs baseline: 3.8613x; 1.3357x over previous
//
#include <hip/hip_runtime.h>
#include <hip/hip_bf16.h>
#include <math.h>

#define L_IN 1549
#define S_OUT 512

typedef __hip_bfloat16 bf16;
typedef __attribute__((ext_vector_type(8))) short bfrag;    // 8 bf16 (4 VGPRs)
typedef __attribute__((ext_vector_type(4))) float f32x4;    // MFMA accumulator

__device__ __forceinline__ float bfbits2f(unsigned short u) {
    union { unsigned int i; float f; } x;
    x.i = ((unsigned int)u) << 16;
    return x.f;
}
__device__ __forceinline__ unsigned short f2bfbits(float f) {
    union { float f; unsigned int i; } x; x.f = f;
    unsigned int lsb = (x.i >> 16) & 1;
    return (unsigned short)((x.i + 0x7fff + lsb) >> 16);
}

// bf16-pair dot product: c + lo(w)*lo(h) + hi(w)*hi(h)
#if __has_builtin(__builtin_amdgcn_fdot2_f32_bf16)
typedef __attribute__((ext_vector_type(2))) __bf16 v2bf;
__device__ __forceinline__ float dot2bf(unsigned int w, unsigned int h, float c) {
    union { unsigned int u; v2bf v; } a, b;
    a.u = w; b.u = h;
    return __builtin_amdgcn_fdot2_f32_bf16(a.v, b.v, c, false);
}
#else
__device__ __forceinline__ float dot2bf(unsigned int w, unsigned int h, float c) {
    union { unsigned int i; float f; } w0, w1, h0, h1;
    w0.i = w << 16; w1.i = w & 0xffff0000u;
    h0.i = h << 16; h1.i = h & 0xffff0000u;
    return c + w0.f * h0.f + w1.f * h1.f;
}
#endif

// ---------------------------------------------------------------------------
// conv1d(k=16,pad=1) + BN + ReLU + maxpool(3,3) + transpose -> h0 (B,512,32) bf16
// ---------------------------------------------------------------------------
__global__ __launch_bounds__(256) void conv_bn_pool(
    const float* __restrict__ x, const float* __restrict__ w,
    const float* __restrict__ cb, const float* __restrict__ gamma,
    const float* __restrict__ beta, const float* __restrict__ mean,
    const float* __restrict__ var, bf16* __restrict__ h0)
{
    int b  = blockIdx.y;
    int sg = blockIdx.x;
    __shared__ float xs[32][40];
    int tid = threadIdx.x;
    int base = sg * 24;
    for (int i = tid; i < 32 * 40; i += 256) {
        int ci = i / 40, dl = i % 40;
        int l = base - 1 + dl;
        xs[ci][dl] = (l >= 0 && l < L_IN) ? x[(size_t)(b * 32 + ci) * L_IN + l] : 0.f;
    }
    __syncthreads();
    int c = tid & 31, sl = tid >> 5;
    float scale = gamma[c] * rsqrtf(var[c] + 1e-5f);
    float shift = beta[c] - mean[c] * scale;
    float bias = cb[c];
    float best = -1e30f;
    #pragma unroll
    for (int p = 0; p < 3; ++p) {
        float acc = bias;
        for (int ci = 0; ci < 32; ++ci) {
            const float* wr = w + (size_t)(c * 32 + ci) * 16;
            int off = 3 * sl + p;
            #pragma unroll
            for (int kk = 0; kk < 16; ++kk) acc += xs[ci][off + kk] * wr[kk];
        }
        float y = acc * scale + shift;
        y = fmaxf(y, 0.f);
        best = fmaxf(best, y);
    }
    int s = sg * 8 + sl;
    h0[((size_t)b * S_OUT + s) * 32 + c] = __float2bfloat16(best);
}

// ---------------------------------------------------------------------------
// fp32 -> bf16 elementwise pack
// ---------------------------------------------------------------------------
__global__ void pack_bf16(const float* __restrict__ src, bf16* __restrict__ dst, int n)
{
    int i = blockIdx.x * 256 + threadIdx.x;
    if (i < n) dst[i] = __float2bfloat16(src[i]);
}

// ---------------------------------------------------------------------------
// Pack W_hh (1024,256) fp32 for lstm_reg.  (unchanged from round 6)
// ---------------------------------------------------------------------------
__global__ void pack_lstm(const float* __restrict__ W, unsigned int* __restrict__ out)
{
    int i = blockIdx.x * 256 + threadIdx.x;   // 0..131071
    int kp, t, col;
    if (i < 102400) {
        kp = i >> 10; col = (i >> 9) & 1; t = i & 511;
    } else if (i < 116736) {
        int j = i - 102400;
        kp = 100 + (j >> 10); t = (j & 1023) >> 1; col = j & 1;
    } else {
        int j = i - 116736;
        kp = 114 + (j >> 10); t = (j & 1023) >> 1; col = j & 1;
    }
    int g = 2 * t + col;
    unsigned int lo = f2bfbits(W[(size_t)g * 256 + 2 * kp]);
    unsigned int hi = f2bfbits(W[(size_t)g * 256 + 2 * kp + 1]);
    out[i] = lo | (hi << 16);
}

// ---------------------------------------------------------------------------
// MFMA bf16 GEMM:  C = A @ B^T + bias.  (unchanged from round 4)
// ---------------------------------------------------------------------------
__global__ __launch_bounds__(256) void gemm_mfma(
    const bf16* __restrict__ A,
    const bf16* __restrict__ Bm0, const bf16* __restrict__ Bm1, const bf16* __restrict__ Bm2,
    const float* __restrict__ bs0, const float* __restrict__ bs1, const float* __restrict__ bs2,
    bf16* __restrict__ Cm0, bf16* __restrict__ Cm1, bf16* __restrict__ Cm2,
    int M, int N, int K)
{
    int z = blockIdx.z;
    const bf16* B = (z == 0) ? Bm0 : ((z == 1) ? Bm1 : Bm2);
    const float* bias = (z == 0) ? bs0 : ((z == 1) ? bs1 : bs2);
    bf16* C = (z == 0) ? Cm0 : ((z == 1) ? Cm1 : Cm2);

    __shared__ bf16 As[128 * 32];
    __shared__ bf16 Bs[128 * 32];

    int tid = threadIdx.x;
    int lane = tid & 63;
    int wave = tid >> 6;
    int bm = blockIdx.y, bn = blockIdx.x;
    int wm = (wave >> 1) * 64;
    int wn = (wave & 1) * 64;

    int sr = tid >> 2;
    int sc = (tid & 3) * 8;
    const bf16* Ag = A + (size_t)(bm * 128 + sr) * K + sc;
    const bf16* Bg = B + (size_t)(bn * 128 + sr) * K + sc;

    int fm = lane & 15;
    int fk = (lane >> 4) * 8;

    f32x4 acc[4][4];
    #pragma unroll
    for (int i = 0; i < 4; ++i)
        #pragma unroll
        for (int j = 0; j < 4; ++j) acc[i][j] = (f32x4)(0.f);

    for (int k0 = 0; k0 < K; k0 += 32) {
        float4 a0 = *(const float4*)(Ag + k0);
        float4 a1 = *(const float4*)(Ag + (size_t)64 * K + k0);
        float4 b0 = *(const float4*)(Bg + k0);
        float4 b1 = *(const float4*)(Bg + (size_t)64 * K + k0);
        __syncthreads();
        *(float4*)(As + sr * 32 + sc)        = a0;
        *(float4*)(As + (sr + 64) * 32 + sc) = a1;
        *(float4*)(Bs + sr * 32 + sc)        = b0;
        *(float4*)(Bs + (sr + 64) * 32 + sc) = b1;
        __syncthreads();

        bfrag af[4], bfr[4];
        #pragma unroll
        for (int i = 0; i < 4; ++i)
            af[i] = *(const bfrag*)(As + (wm + i * 16 + fm) * 32 + fk);
        #pragma unroll
        for (int j = 0; j < 4; ++j)
            bfr[j] = *(const bfrag*)(Bs + (wn + j * 16 + fm) * 32 + fk);
        #pragma unroll
        for (int i = 0; i < 4; ++i)
            #pragma unroll
            for (int j = 0; j < 4; ++j)
                acc[i][j] = __builtin_amdgcn_mfma_f32_16x16x32_bf16(
                    af[i], bfr[j], acc[i][j], 0, 0, 0);
    }

    int rbase = (lane >> 4) * 4;
    #pragma unroll
    for (int j = 0; j < 4; ++j) {
        int n = bn * 128 + wn + j * 16 + (lane & 15);
        float bv = bias[n];
        #pragma unroll
        for (int i = 0; i < 4; ++i) {
            #pragma unroll
            for (int r = 0; r < 4; ++r) {
                int m = bm * 128 + wm + i * 16 + rbase + r;
                C[(size_t)m * N + n] = __float2bfloat16(acc[i][j][r] + bv);
            }
        }
    }
}

// ---------------------------------------------------------------------------
// LSTM recurrence v4: on-chip weights (unchanged from round 6).
// ---------------------------------------------------------------------------
__global__ __launch_bounds__(512, 2) void lstm_reg(
    const bf16* __restrict__ xg_f, const bf16* __restrict__ xg_b,
    const unsigned int* __restrict__ Wl, bf16* __restrict__ out)
{
    int u = blockIdx.x;          // 0..127
    int b = u & 63, dir = u >> 6;
    const unsigned int* W = Wl + (size_t)dir * 131072;
    const bf16* xg = dir ? xg_b : xg_f;
    int t = threadIdx.x;         // 0..511

    __shared__ unsigned int lw[14336];               // 56 KB weight slice
    __shared__ __align__(16) unsigned int hs2[128];  // h bf16 pairs
    __shared__ float gsh[1024];                      // gates

    unsigned int wr[200];
    #pragma unroll
    for (int j = 0; j < 200; ++j) wr[j] = W[j * 512 + t];
    for (int i = t; i < 14336; i += 512) lw[i] = W[102400 + i];
    if (t < 128) hs2[t] = 0u;
    float c0 = 0.f, c1 = 0.f;
    __syncthreads();

    const unsigned int* Wst = W + 116736;

    for (int step = 0; step < 512; ++step) {
        int ts = dir ? (511 - step) : step;

        uint2 sw[14];
        #pragma unroll
        for (int s = 0; s < 14; ++s)
            sw[s] = *(const uint2*)(Wst + s * 1024 + 2 * t);
        unsigned int xv =
            *(const unsigned int*)(xg + ((size_t)b * 512 + ts) * 1024 + 2 * t);

        float a0 = 0.f, a1 = 0.f;
        #pragma unroll
        for (int q = 0; q < 25; ++q) {
            uint4 hv = *(const uint4*)&hs2[q * 4];
            #pragma unroll
            for (int r = 0; r < 4; ++r) {
                int kp = q * 4 + r;
                unsigned int h2 = (&hv.x)[r];
                a0 = dot2bf(wr[kp * 2], h2, a0);
                a1 = dot2bf(wr[kp * 2 + 1], h2, a1);
            }
        }
        #pragma unroll
        for (int r = 0; r < 14; ++r) {
            uint2 wv = *(const uint2*)&lw[r * 1024 + 2 * t];
            unsigned int h2 = hs2[100 + r];
            a0 = dot2bf(wv.x, h2, a0);
            a1 = dot2bf(wv.y, h2, a1);
        }
        #pragma unroll
        for (int s = 0; s < 14; ++s) {
            unsigned int h2 = hs2[114 + s];
            a0 = dot2bf(sw[s].x, h2, a0);
            a1 = dot2bf(sw[s].y, h2, a1);
        }
        a0 += bfbits2f((unsigned short)(xv & 0xffff));
        a1 += bfbits2f((unsigned short)(xv >> 16));

        __syncthreads();
        *(float2*)&gsh[2 * t] = make_float2(a0, a1);
        __syncthreads();

        if (t < 128) {
            float gi0 = gsh[2 * t],       gi1 = gsh[2 * t + 1];
            float gf0 = gsh[256 + 2 * t], gf1 = gsh[257 + 2 * t];
            float gg0 = gsh[512 + 2 * t], gg1 = gsh[513 + 2 * t];
            float go0 = gsh[768 + 2 * t], go1 = gsh[769 + 2 * t];
            float si0 = 1.f / (1.f + expf(-gi0)), si1 = 1.f / (1.f + expf(-gi1));
            float sf0 = 1.f / (1.f + expf(-gf0)), sf1 = 1.f / (1.f + expf(-gf1));
            float so0 = 1.f / (1.f + expf(-go0)), so1 = 1.f / (1.f + expf(-go1));
            c0 = sf0 * c0 + si0 * tanhf(gg0);
            c1 = sf1 * c1 + si1 * tanhf(gg1);
            float h0 = so0 * tanhf(c0);
            float h1 = so1 * tanhf(c1);
            unsigned int hp = (unsigned int)f2bfbits(h0)
                            | ((unsigned int)f2bfbits(h1) << 16);
            hs2[t] = hp;
            *(unsigned int*)(out + ((size_t)b * 512 + ts) * 512 + dir * 256 + 2 * t) = hp;
        }
        __syncthreads();
    }
}

// ---------------------------------------------------------------------------
// V transpose: vt[b][n][s] = v[b][s][n]   (64x64 tiles via LDS)
// ---------------------------------------------------------------------------
__global__ __launch_bounds__(256) void vt_transpose(
    const bf16* __restrict__ v, bf16* __restrict__ vt)
{
    __shared__ unsigned short tile[64 * 73];
    int b = blockIdx.z;
    int s0 = blockIdx.x * 64, n0 = blockIdx.y * 64;
    int tid = threadIdx.x;
    #pragma unroll
    for (int u = 0; u < 2; ++u) {
        int idx = tid + u * 256;
        int si = idx >> 3, nj = (idx & 7) << 3;
        bfrag val = *(const bfrag*)(v + ((size_t)(b * 512 + s0 + si)) * 512 + n0 + nj);
        #pragma unroll
        for (int jj = 0; jj < 8; ++jj)
            tile[(nj + jj) * 73 + si] = ((unsigned short*)&val)[jj];
    }
    __syncthreads();
    #pragma unroll
    for (int u = 0; u < 2; ++u) {
        int idx = tid + u * 256;
        int ni = idx >> 3, sj = (idx & 7) << 3;
        unsigned short outv[8];
        #pragma unroll
        for (int jj = 0; jj < 8; ++jj)
            outv[jj] = tile[ni * 73 + sj + jj];
        *(float4*)(vt + (size_t)b * 262144 + (size_t)(n0 + ni) * 512 + s0 + sj) =
            *(float4*)outv;
    }
}

// ---------------------------------------------------------------------------
// MFMA attention v3 — no LDS, no barriers.
// Block = (b, 32 s-rows); 4 waves = 2 s-subtiles x 2 d-halves.
// Scores computed TRANSPOSED (m=t, n=s) per head: C' col = s = lane&15,
// row = t.  A-lane m loads k-row t = tc + tile*4 + 8*(m>>2) + (m&3), so the
// lane's 8 score regs (2 tiles x 4) are exactly the PV A-frag elements
// k = quad*8 + (tile*4+reg) — log-softmax over heads is elementwise in regs
// and P repacks in-lane to bf16.  PV: A = P, B = vt[n=d][k=t] (global 16B).
// ctx C: col = d, row = s -> coalesced residual add into r (in-place o1).
// ---------------------------------------------------------------------------
__global__ __launch_bounds__(256, 2) void attention_mfma(
    const bf16* __restrict__ q, const bf16* __restrict__ k,
    const bf16* __restrict__ vt, bf16* r)
{
    int b = blockIdx.y;
    int s0 = blockIdx.x * 32;
    int tid = threadIdx.x;
    int wave = tid >> 6;
    int sw = wave & 1, dh = wave >> 1;
    int lane = tid & 63;
    int L15 = lane & 15, quad = lane >> 4;

    // Q B-frags (n = s = lane&15): once
    const bf16* qrow = q + ((size_t)(b * 512 + s0 + sw * 16 + L15)) * 512;
    bfrag qf[8][2];
    #pragma unroll
    for (int h = 0; h < 8; ++h) {
        qf[h][0] = *(const bfrag*)(qrow + h * 64 + quad * 8);
        qf[h][1] = *(const bfrag*)(qrow + h * 64 + 32 + quad * 8);
    }

    f32x4 ctxa[8][2];
    #pragma unroll
    for (int h = 0; h < 8; ++h) {
        ctxa[h][0] = (f32x4)(0.f);
        ctxa[h][1] = (f32x4)(0.f);
    }

    int tperm = ((L15 >> 2) << 3) + (L15 & 3);   // row m -> t offset
    const bf16* kbase = k + (size_t)(b * 512) * 512;
    const bf16* vbase = vt + (size_t)b * 262144;

    for (int tc = 0; tc < 512; tc += 32) {
        // scores S^T, all 8 heads, 2 t-subtiles (permuted rows)
        f32x4 sa[8][2];
        #pragma unroll
        for (int h = 0; h < 8; ++h) {
            #pragma unroll
            for (int tile = 0; tile < 2; ++tile) {
                const bf16* krow = kbase
                    + (size_t)(tc + tile * 4 + tperm) * 512 + h * 64 + quad * 8;
                bfrag a0 = *(const bfrag*)(krow);
                bfrag a1 = *(const bfrag*)(krow + 32);
                f32x4 acc = __builtin_amdgcn_mfma_f32_16x16x32_bf16(
                    a0, qf[h][0], (f32x4)(0.f), 0, 0, 0);
                acc = __builtin_amdgcn_mfma_f32_16x16x32_bf16(
                    a1, qf[h][1], acc, 0, 0, 0);
                sa[h][tile] = acc;
            }
        }
        // log-softmax over the 8 heads, elementwise per (tile, reg)
        bfrag pf[8];
        #pragma unroll
        for (int tile = 0; tile < 2; ++tile) {
            #pragma unroll
            for (int rr = 0; rr < 4; ++rr) {
                float sc[8];
                float m = -1e30f;
                #pragma unroll
                for (int h = 0; h < 8; ++h) {
                    sc[h] = sa[h][tile][rr] * 0.125f;
                    m = fmaxf(m, sc[h]);
                }
                float sum = 0.f;
                #pragma unroll
                for (int h = 0; h < 8; ++h) sum += expf(sc[h] - m);
                float lse = m + logf(sum);
                #pragma unroll
                for (int h = 0; h < 8; ++h)
                    ((unsigned short*)&pf[h])[tile * 4 + rr] = f2bfbits(sc[h] - lse);
            }
        }
        // PV: ctx[s][d] += P[s][t] * V[t][d]
        #pragma unroll
        for (int h = 0; h < 8; ++h) {
            #pragma unroll
            for (int dt = 0; dt < 2; ++dt) {
                int n = h * 64 + dh * 32 + dt * 16 + L15;
                bfrag vf = *(const bfrag*)(vbase + (size_t)n * 512 + tc + quad * 8);
                ctxa[h][dt] = __builtin_amdgcn_mfma_f32_16x16x32_bf16(
                    pf[h], vf, ctxa[h][dt], 0, 0, 0);
            }
        }
    }
    // epilogue: r = o1 + ctx (in-place; each element owned by one lane)
    #pragma unroll
    for (int h = 0; h < 8; ++h) {
        #pragma unroll
        for (int dt = 0; dt < 2; ++dt) {
            int n = h * 64 + dh * 32 + dt * 16 + L15;
            #pragma unroll
            for (int rr = 0; rr < 4; ++rr) {
                size_t addr =
                    ((size_t)(b * 512 + s0 + sw * 16 + quad * 4 + rr)) * 512 + n;
                float o = __bfloat162float(r[addr]);
                r[addr] = __float2bfloat16(o + ctxa[h][dt][rr]);
            }
        }
    }
}

// ---------------------------------------------------------------------------
// LayerNorm(last dim) -> mean over S -> fc.  One block per (b, s) row.
// ---------------------------------------------------------------------------
__device__ __forceinline__ float block_sum(float val, float* red, int tid)
{
    #pragma unroll
    for (int o = 32; o > 0; o >>= 1) val += __shfl_down(val, o);
    __syncthreads();
    if ((tid & 63) == 0) red[tid >> 6] = val;
    __syncthreads();
    return red[0] + red[1] + red[2] + red[3];
}

__global__ __launch_bounds__(256) void ln_pool_fc(
    const bf16* __restrict__ r, const float* __restrict__ g, const float* __restrict__ bt,
    const float* __restrict__ fcw, const float* __restrict__ fcb, float* __restrict__ out)
{
    __shared__ float red[4];
    int b = blockIdx.y, s = blockIdx.x, tid = threadIdx.x;
    const bf16* row = r + ((size_t)(b * 512 + s)) * 512;
    __hip_bfloat162 rv = *(const __hip_bfloat162*)(row + tid * 2);
    float v0 = __bfloat162float(rv.x), v1 = __bfloat162float(rv.y);
    float tot = block_sum(v0 + v1, red, tid);
    float mu = tot * (1.f / 512.f);
    float d0 = v0 - mu, d1 = v1 - mu;
    float sq = block_sum(d0 * d0 + d1 * d1, red, tid);
    float rs = rsqrtf(sq * (1.f / 512.f) + 1e-5f);
    int n0 = tid * 2;
    float term = d0 * rs * g[n0] * fcw[n0] + d1 * rs * g[n0 + 1] * fcw[n0 + 1];
    if (s == 0) term += 512.f * (bt[n0] * fcw[n0] + bt[n0 + 1] * fcw[n0 + 1]);
    float D = block_sum(term, red, tid);
    if (tid == 0) {
        float val = D * (1.f / 512.f);
        if (s == 0) val += fcb[0];
        atomicAdd(out + b, val);
    }
}

// ---------------------------------------------------------------------------
// Workspace layout (< 200 MiB):
//   [0,64M)        xgf bf16            -> later q,k
//   [64,128M)      xgb bf16            -> later v
//   [128,160M)     out0 bf16           -> later vt (V transposed)
//   [160,192M)     out1 bf16 (attention in-place)
//   [192,194M)     h0 bf16
//   [194,196M)     wl0/wl1 (2 x 262,144 dwords)
//   then bf16 proj weights
// ---------------------------------------------------------------------------
extern "C" void kernel_launch(void* const* d_in, const int* in_sizes, int n_in,
                              void* d_out, int out_size, void* d_ws, size_t ws_size,
                              hipStream_t stream)
{
    (void)in_sizes; (void)n_in; (void)ws_size;
    const float* x      = (const float*)d_in[0];
    const float* conv_w = (const float*)d_in[1];
    const float* conv_b = (const float*)d_in[2];
    const float* bn_g   = (const float*)d_in[3];
    const float* bn_b   = (const float*)d_in[4];
    const float* bn_m   = (const float*)d_in[5];
    const float* bn_v   = (const float*)d_in[6];
    const float* W_ih0f = (const float*)d_in[7];
    const float* W_hh0f = (const float*)d_in[8];
    const float* b0f    = (const float*)d_in[9];
    const float* W_ih0b = (const float*)d_in[10];
    const float* W_hh0b = (const float*)d_in[11];
    const float* b0b    = (const float*)d_in[12];
    const float* W_ih1f = (const float*)d_in[13];
    const float* W_hh1f = (const float*)d_in[14];
    const float* b1f    = (const float*)d_in[15];
    const float* W_ih1b = (const float*)d_in[16];
    const float* W_hh1b = (const float*)d_in[17];
    const float* b1b    = (const float*)d_in[18];
    const float* Wq = (const float*)d_in[19];
    const float* bq = (const float*)d_in[20];
    const float* Wk = (const float*)d_in[21];
    const float* bk = (const float*)d_in[22];
    const float* Wv = (const float*)d_in[23];
    const float* bv = (const float*)d_in[24];
    const float* ln_g = (const float*)d_in[25];
    const float* ln_b = (const float*)d_in[26];
    const float* fc_w = (const float*)d_in[27];
    const float* fc_b = (const float*)d_in[28];
    float* out = (float*)d_out;

    char* ws = (char*)d_ws;
    bf16* xgf  = (bf16*)ws;                               // 33,554,432
    bf16* xgb  = xgf + 33554432;                          // 33,554,432
    bf16* out0 = (bf16*)(ws + 134217728);                 // 16,777,216
    bf16* out1 = (bf16*)(ws + 167772160);                 // 16,777,216
    bf16* h0   = (bf16*)(ws + 201326592);                 // 1,048,576
    unsigned int* wl0 = (unsigned int*)(ws + 203423744);  // 262,144 dwords
    unsigned int* wl1 = wl0 + 262144;                     // 262,144 dwords
    bf16* wbih0f = (bf16*)(wl1 + 262144);                 // 32,768
    bf16* wbih0b = wbih0f + 32768;                        // 32,768
    bf16* wbih1f = wbih0b + 32768;                        // 524,288
    bf16* wbih1b = wbih1f + 524288;                       // 524,288
    bf16* wbq    = wbih1b + 524288;                       // 262,144
    bf16* wbk    = wbq + 262144;                          // 262,144
    bf16* wbv    = wbk + 262144;                          // 262,144
    // q,k,v alias the (dead after lstm1) xg region; vt aliases dead out0
    bf16* qb = xgf;
    bf16* kb = xgf + 16777216;
    bf16* vb = xgb;
    bf16* vtb = out0;

    hipMemsetAsync(d_out, 0, (size_t)out_size * sizeof(float), stream);

    pack_lstm<<<512, 256, 0, stream>>>(W_hh0f, wl0);
    pack_lstm<<<512, 256, 0, stream>>>(W_hh0b, wl0 + 131072);
    pack_lstm<<<512, 256, 0, stream>>>(W_hh1f, wl1);
    pack_lstm<<<512, 256, 0, stream>>>(W_hh1b, wl1 + 131072);
    pack_bf16<<<128, 256, 0, stream>>>(W_ih0f, wbih0f, 32768);
    pack_bf16<<<128, 256, 0, stream>>>(W_ih0b, wbih0b, 32768);
    pack_bf16<<<2048, 256, 0, stream>>>(W_ih1f, wbih1f, 524288);
    pack_bf16<<<2048, 256, 0, stream>>>(W_ih1b, wbih1b, 524288);
    pack_bf16<<<1024, 256, 0, stream>>>(Wq, wbq, 262144);
    pack_bf16<<<1024, 256, 0, stream>>>(Wk, wbk, 262144);
    pack_bf16<<<1024, 256, 0, stream>>>(Wv, wbv, 262144);

    conv_bn_pool<<<dim3(64, 64), 256, 0, stream>>>(
        x, conv_w, conv_b, bn_g, bn_b, bn_m, bn_v, h0);

    // layer-0 input projections (K=32), fwd+bwd in one launch
    gemm_mfma<<<dim3(8, 256, 2), 256, 0, stream>>>(
        h0, wbih0f, wbih0b, nullptr, b0f, b0b, nullptr, xgf, xgb, nullptr,
        32768, 1024, 32);

    lstm_reg<<<128, 512, 0, stream>>>(xgf, xgb, wl0, out0);

    // layer-1 input projections (K=512)
    gemm_mfma<<<dim3(8, 256, 2), 256, 0, stream>>>(
        out0, wbih1f, wbih1b, nullptr, b1f, b1b, nullptr, xgf, xgb, nullptr,
        32768, 1024, 512);

    lstm_reg<<<128, 512, 0, stream>>>(xgf, xgb, wl1, out1);

    // QKV projections (N=512), 3-way
    gemm_mfma<<<dim3(4, 256, 3), 256, 0, stream>>>(
        out1, wbq, wbk, wbv, bq, bk, bv, qb, kb, vb,
        32768, 512, 512);

    vt_transpose<<<dim3(8, 8, 64), 256, 0, stream>>>(vb, vtb);

    attention_mfma<<<dim3(16, 64), 256, 0, stream>>>(qb, kb, vtb, out1);

    ln_pool_fc<<<dim3(512, 64), 256, 0, stream>>>(out1, ln_g, ln_b, fc_w, fc_b, out);
}